// Round 5
// baseline (156608.606 us; speedup 1.0000x reference)
//
#include <hip/hip_runtime.h>

// Persistent-kernel multilayer GRU, all f32.
// 256 blocks x 512 threads, exactly 1 block/CU (LDS-limited) => co-resident.
// Each block owns 4 j-rows of H=1024. Recurrent weights (Whz,Whr,Whg x 3
// layers; 4 rows x 1024 each) live in LDS (147,456 B) + 13,824 B scratch.
// Grid-wide sync: monotonic atomic counter + __threadfence (agent scope:
// L2 writeback on release, L1/L2 invalidate on acquire => cross-XCD safe).

struct GruParams {
  const float* x;            // (B=32, S=512, I=128)
  const float* Wx[3][3];     // [layer][gate z,r,g]
  const float* Wh[3][3];
  const float* bias[3][3];
  const float* Wout;         // (128, 1024)
  const float* bout;         // (128)
  float* hT;                 // [3][1024][32]  (k-major, b-minor)
  float* rhT;                // [1024][32]
  unsigned* cnt;             // grid barrier counter
  float* out;                // (B,S,O)
  float* outHid;             // (B,L,H)
};

#define NBLK 256
#define WFLOATS 36864              // 9 slices * 4 rows * 1024
#define SFLOATS 3456               // 8*384 partials + 384 combine
#define LDSB ((WFLOATS + SFLOATS) * 4)   // 161,280 B

extern __shared__ float lds[];

__device__ __forceinline__ void gridbar(unsigned* cnt, unsigned target) {
  __syncthreads();                     // all waves' stores drained (vmcnt 0)
  if (threadIdx.x == 0) {
    __threadfence();                   // release: XCD L2 writeback
    atomicAdd(cnt, 1u);
    while (__hip_atomic_load(cnt, __ATOMIC_RELAXED, __HIP_MEMORY_SCOPE_AGENT) < target)
      __builtin_amdgcn_s_sleep(1);
  }
  __syncthreads();
  __threadfence();                     // acquire: invalidate stale L1/L2
}

__global__ __launch_bounds__(512, 2) void gruPersist(GruParams p) {
  const int tid  = threadIdx.x;
  const int bid  = blockIdx.x;
  const int w    = tid >> 6;        // wave 0..7
  const int lane = tid & 63;
  const int b    = lane & 31;       // batch
  const int ks   = lane >> 5;       // k-subslice 0/1
  const int jbase = bid << 2;
  float* scratch = lds + WFLOATS;

  // ---- Stage 0: cache this block's Wh slices in LDS (coalesced) ----
  for (int idx = tid; idx < WFLOATS; idx += 512) {
    const int slice = idx >> 12;           // layer*3 + gate
    const int rem   = idx & 4095;          // jj*1024 + k
    const int l = slice / 3, m = slice - l * 3;
    lds[idx] = p.Wh[l][m][((size_t)jbase << 10) + rem];
  }
  __syncthreads();

  unsigned phase = 0;
  float my_z = 0.f, my_gx = 0.f;    // valid for tid<128, carried A->C

  for (int t = 0; t < 512; ++t) {
    for (int l = 0; l < 3; ++l) {
      float* hTl = p.hT + l * 32768;

      // ================= Stage A =================
      float az[4] = {0.f,0.f,0.f,0.f};
      float ar[4] = {0.f,0.f,0.f,0.f};
      float ag[4] = {0.f,0.f,0.f,0.f};

      // h-side (K=1024), weights from LDS (wave-broadcast, 2 addrs)
      {
        const float* wzl = lds + (l * 3 + 0) * 4096;
        const float* wrl = lds + (l * 3 + 1) * 4096;
        #pragma unroll 4
        for (int i = 0; i < 16; ++i) {
          const int k = (w << 7) + (i << 3) + (ks << 2);
          const float o0 = hTl[(k + 0) * 32 + b];
          const float o1 = hTl[(k + 1) * 32 + b];
          const float o2 = hTl[(k + 2) * 32 + b];
          const float o3 = hTl[(k + 3) * 32 + b];
          #pragma unroll
          for (int jj = 0; jj < 4; ++jj) {
            const float4 a = *(const float4*)(wzl + (jj << 10) + k);
            const float4 c = *(const float4*)(wrl + (jj << 10) + k);
            az[jj] += o0 * a.x; az[jj] += o1 * a.y;
            az[jj] += o2 * a.z; az[jj] += o3 * a.w;
            ar[jj] += o0 * c.x; ar[jj] += o1 * c.y;
            ar[jj] += o2 * c.z; ar[jj] += o3 * c.w;
          }
        }
      }

      // x-side
      if (l == 0) {
        const float* xb = p.x + ((size_t)b << 16) + ((size_t)t << 7);
        #pragma unroll
        for (int i = 0; i < 2; ++i) {
          const int k = (w << 4) + (i << 3) + (ks << 2);
          const float o0 = xb[k + 0], o1 = xb[k + 1];
          const float o2 = xb[k + 2], o3 = xb[k + 3];
          #pragma unroll
          for (int jj = 0; jj < 4; ++jj) {
            const size_t row = (size_t)(jbase + jj) * 128 + k;
            const float4 a = *(const float4*)(p.Wx[0][0] + row);
            const float4 c = *(const float4*)(p.Wx[0][1] + row);
            const float4 d = *(const float4*)(p.Wx[0][2] + row);
            az[jj] += o0 * a.x; az[jj] += o1 * a.y;
            az[jj] += o2 * a.z; az[jj] += o3 * a.w;
            ar[jj] += o0 * c.x; ar[jj] += o1 * c.y;
            ar[jj] += o2 * c.z; ar[jj] += o3 * c.w;
            ag[jj] += o0 * d.x; ag[jj] += o1 * d.y;
            ag[jj] += o2 * d.z; ag[jj] += o3 * d.w;
          }
        }
      } else {
        const float* inT = p.hT + (l - 1) * 32768;
        const float* wxz = p.Wx[l][0];
        const float* wxr = p.Wx[l][1];
        const float* wxg = p.Wx[l][2];
        #pragma unroll 2
        for (int i = 0; i < 16; ++i) {
          const int k = (w << 7) + (i << 3) + (ks << 2);
          const float o0 = inT[(k + 0) * 32 + b];
          const float o1 = inT[(k + 1) * 32 + b];
          const float o2 = inT[(k + 2) * 32 + b];
          const float o3 = inT[(k + 3) * 32 + b];
          #pragma unroll
          for (int jj = 0; jj < 4; ++jj) {
            const size_t row = ((size_t)(jbase + jj) << 10) + k;
            const float4 a = *(const float4*)(wxz + row);
            const float4 c = *(const float4*)(wxr + row);
            const float4 d = *(const float4*)(wxg + row);
            az[jj] += o0 * a.x; az[jj] += o1 * a.y;
            az[jj] += o2 * a.z; az[jj] += o3 * a.w;
            ar[jj] += o0 * c.x; ar[jj] += o1 * c.y;
            ar[jj] += o2 * c.z; ar[jj] += o3 * c.w;
            ag[jj] += o0 * d.x; ag[jj] += o1 * d.y;
            ag[jj] += o2 * d.z; ag[jj] += o3 * d.w;
          }
        }
      }

      // reduce: ks pair, then 8 waves via LDS
      #pragma unroll
      for (int jj = 0; jj < 4; ++jj) {
        az[jj] += __shfl_xor(az[jj], 32);
        ar[jj] += __shfl_xor(ar[jj], 32);
        ag[jj] += __shfl_xor(ag[jj], 32);
      }
      if (ks == 0) {
        #pragma unroll
        for (int jj = 0; jj < 4; ++jj) {
          scratch[w * 384 + (jj * 3 + 0) * 32 + b] = az[jj];
          scratch[w * 384 + (jj * 3 + 1) * 32 + b] = ar[jj];
          scratch[w * 384 + (jj * 3 + 2) * 32 + b] = ag[jj];
        }
      }
      __syncthreads();
      if (tid < 384) {
        float s = 0.f;
        #pragma unroll
        for (int ww = 0; ww < 8; ++ww) s += scratch[ww * 384 + tid];
        scratch[3072 + tid] = s;
      }
      __syncthreads();
      if (tid < 128) {
        const int jj = tid >> 5, bb = tid & 31;
        const int j = jbase + jj;
        const float zp = scratch[3072 + (jj * 3 + 0) * 32 + bb] + p.bias[l][0][j];
        const float rp = scratch[3072 + (jj * 3 + 1) * 32 + bb] + p.bias[l][1][j];
        const float gp = scratch[3072 + (jj * 3 + 2) * 32 + bb] + p.bias[l][2][j];
        const float z = 1.f / (1.f + expf(-zp));
        const float r = 1.f / (1.f + expf(-rp));
        my_z  = z;
        my_gx = gp;
        p.rhT[(j << 5) + bb] = r * hTl[(j << 5) + bb];
      }
      ++phase;
      gridbar(p.cnt, 256u * phase);

      // ================= Stage C =================
      float ac[4] = {0.f,0.f,0.f,0.f};
      {
        const float* wgl = lds + (l * 3 + 2) * 4096;
        #pragma unroll 4
        for (int i = 0; i < 16; ++i) {
          const int k = (w << 7) + (i << 3) + (ks << 2);
          const float o0 = p.rhT[(k + 0) * 32 + b];
          const float o1 = p.rhT[(k + 1) * 32 + b];
          const float o2 = p.rhT[(k + 2) * 32 + b];
          const float o3 = p.rhT[(k + 3) * 32 + b];
          #pragma unroll
          for (int jj = 0; jj < 4; ++jj) {
            const float4 g4 = *(const float4*)(wgl + (jj << 10) + k);
            ac[jj] += o0 * g4.x; ac[jj] += o1 * g4.y;
            ac[jj] += o2 * g4.z; ac[jj] += o3 * g4.w;
          }
        }
      }
      #pragma unroll
      for (int jj = 0; jj < 4; ++jj) ac[jj] += __shfl_xor(ac[jj], 32);
      if (ks == 0) {
        #pragma unroll
        for (int jj = 0; jj < 4; ++jj)
          scratch[w * 128 + jj * 32 + b] = ac[jj];
      }
      __syncthreads();
      if (tid < 128) {
        float s = 0.f;
        #pragma unroll
        for (int ww = 0; ww < 8; ++ww) s += scratch[ww * 128 + tid];
        const int jj = tid >> 5, bb = tid & 31;
        const int j = jbase + jj;
        const float g  = tanhf(s + my_gx);
        const float hn = my_z * hTl[(j << 5) + bb] + (1.f - my_z) * g;
        hTl[(j << 5) + bb] = hn;
        if (t == 511) p.outHid[bb * 3072 + l * 1024 + j] = hn;
      }
      ++phase;
      gridbar(p.cnt, 256u * phase);
    } // layers

    // ================= Output head (blocks 0..31) =================
    if (bid < 32) {
      const float* h2 = p.hT + 2 * 32768;
      const int obase = bid << 2;
      float ac[4] = {0.f,0.f,0.f,0.f};
      #pragma unroll 2
      for (int i = 0; i < 16; ++i) {
        const int k = (w << 7) + (i << 3) + (ks << 2);
        const float o0 = h2[(k + 0) * 32 + b];
        const float o1 = h2[(k + 1) * 32 + b];
        const float o2 = h2[(k + 2) * 32 + b];
        const float o3 = h2[(k + 3) * 32 + b];
        #pragma unroll
        for (int oo = 0; oo < 4; ++oo) {
          const float4 wv = *(const float4*)(p.Wout + ((size_t)(obase + oo) << 10) + k);
          ac[oo] += o0 * wv.x; ac[oo] += o1 * wv.y;
          ac[oo] += o2 * wv.z; ac[oo] += o3 * wv.w;
        }
      }
      #pragma unroll
      for (int oo = 0; oo < 4; ++oo) ac[oo] += __shfl_xor(ac[oo], 32);
      if (ks == 0) {
        #pragma unroll
        for (int oo = 0; oo < 4; ++oo)
          scratch[w * 128 + oo * 32 + b] = ac[oo];
      }
      __syncthreads();
      if (tid < 128) {
        float s = 0.f;
        #pragma unroll
        for (int ww = 0; ww < 8; ++ww) s += scratch[ww * 128 + tid];
        const int oo = tid >> 5, bb = tid & 31;
        const int o = obase + oo;
        p.out[((size_t)bb << 16) + ((size_t)t << 7) + o] = s + p.bout[o];
      }
      __syncthreads();   // protect scratch before next timestep's stage A
    }
  } // t
}

// Zero h-state and barrier counter (ws is poisoned 0xAA before every launch).
__global__ void initWs(float* hT, unsigned* cnt) {
  const int i = blockIdx.x * 1024 + threadIdx.x;
  if (i < 98304) hT[i] = 0.f;
  if (i == 0) *cnt = 0u;
}

extern "C" void kernel_launch(void* const* d_in, const int* in_sizes, int n_in,
                              void* d_out, int out_size, void* d_ws, size_t ws_size,
                              hipStream_t stream)
{
  GruParams P;
  P.x = (const float*)d_in[0];
  P.Wx[0][0] = (const float*)d_in[1];  P.Wh[0][0] = (const float*)d_in[2];
  P.bias[0][0] = (const float*)d_in[3];
  P.Wx[0][1] = (const float*)d_in[4];  P.Wh[0][1] = (const float*)d_in[5];
  P.bias[0][1] = (const float*)d_in[6];
  P.Wx[0][2] = (const float*)d_in[7];  P.Wh[0][2] = (const float*)d_in[8];
  P.bias[0][2] = (const float*)d_in[9];
  for (int l = 1; l < 3; ++l) {
    const size_t off = (size_t)(l - 1) * 1048576;
    const size_t ob  = (size_t)(l - 1) * 1024;
    P.Wx[l][0] = (const float*)d_in[10] + off; P.Wh[l][0] = (const float*)d_in[11] + off;
    P.bias[l][0] = (const float*)d_in[12] + ob;
    P.Wx[l][1] = (const float*)d_in[13] + off; P.Wh[l][1] = (const float*)d_in[14] + off;
    P.bias[l][1] = (const float*)d_in[15] + ob;
    P.Wx[l][2] = (const float*)d_in[16] + off; P.Wh[l][2] = (const float*)d_in[17] + off;
    P.bias[l][2] = (const float*)d_in[18] + ob;
  }
  P.Wout = (const float*)d_in[19];
  P.bout = (const float*)d_in[20];

  float* ws = (float*)d_ws;
  P.hT  = ws;                         // 3*32768 f32
  P.rhT = ws + 98304;                 // 32768 f32
  P.cnt = (unsigned*)(ws + 131072);
  P.out = (float*)d_out;
  P.outHid = P.out + 2097152;

  hipFuncSetAttribute(reinterpret_cast<const void*>(gruPersist),
                      hipFuncAttributeMaxDynamicSharedMemorySize, LDSB);

  initWs<<<96, 1024, 0, stream>>>(P.hT, P.cnt);
  gruPersist<<<NBLK, 512, LDSB, stream>>>(P);
}

// Round 6
// 31961.469 us; speedup vs baseline: 4.8999x; 4.8999x over previous
//
#include <hip/hip_runtime.h>

// Persistent multilayer GRU, f32, fence-free cross-XCD synchronization.
// 256 blocks x 512 threads, 1 block/CU (LDS-limited) => co-resident (proven r5).
// Recurrent weights (Wh z/r/g x 3 layers, 4 j-rows each) in LDS (147,456 B).
// Cross-block data (hT, rhT, barrier words) uses agent-scope RELAXED atomics
// (sc1: bypasses non-coherent per-XCD L2, served at MALL). No __threadfence:
// __syncthreads' vmcnt(0) drain + atomic arrival gives release ordering; sc1
// loads never see stale L2 lines. => L2 stays warm for streamed Wx weights.

struct GruParams {
  const float* x;            // (B=32, S=512, I=128)
  const float* Wx[3][3];     // [layer][gate z,r,g]
  const float* Wh[3][3];
  const float* bias[3][3];
  const float* Wout;         // (128, 1024)
  const float* bout;         // (128)
  float* hT;                 // [3][1024][32]  (k-major, b-minor)
  float* rhT;                // [1024][32]
  unsigned* bar;             // two-level barrier region
  float* out;                // (B,S,O)
  float* outHid;             // (B,L,H)
};

#define NBLK 256
#define WFLOATS 36864              // 9 slices * 4 rows * 1024
#define SFLOATS 3456               // 8*384 partials + 384 combine
#define LDSB ((WFLOATS + SFLOATS) * 4)   // 161,280 B

extern __shared__ float lds[];

__device__ __forceinline__ float loadc(const float* p) {
  return __hip_atomic_load((float*)p, __ATOMIC_RELAXED, __HIP_MEMORY_SCOPE_AGENT);
}
__device__ __forceinline__ void storec(float* p, float v) {
  __hip_atomic_store(p, v, __ATOMIC_RELAXED, __HIP_MEMORY_SCOPE_AGENT);
}

// bar layout (uints, 128B-strided lines): grp[16] at g*32, root at 512,
// go at 544, grpGo[16] at 576+g*32.
__device__ __forceinline__ void gridbar(unsigned* bar, unsigned phase, int bid) {
  __syncthreads();   // per-wave s_waitcnt vmcnt(0): all stores acked at MALL
  if (threadIdx.x == 0) {
    const int g = bid & 15;
    unsigned* grp   = bar + (g << 5);
    unsigned* root  = bar + 512;
    unsigned* go    = bar + 544;
    unsigned* grpGo = bar + 576 + (g << 5);
    const unsigned tgt = phase << 4;   // cumulative per-line target
    unsigned old = __hip_atomic_fetch_add(grp, 1u, __ATOMIC_RELAXED, __HIP_MEMORY_SCOPE_AGENT);
    if (old == tgt - 1u) {             // last arriver of this group this phase
      unsigned r = __hip_atomic_fetch_add(root, 1u, __ATOMIC_RELAXED, __HIP_MEMORY_SCOPE_AGENT);
      if (r == tgt - 1u) {             // last group
        __hip_atomic_store(go, phase, __ATOMIC_RELAXED, __HIP_MEMORY_SCOPE_AGENT);
      }
      while (__hip_atomic_load(go, __ATOMIC_RELAXED, __HIP_MEMORY_SCOPE_AGENT) < phase)
        __builtin_amdgcn_s_sleep(4);
      __hip_atomic_store(grpGo, phase, __ATOMIC_RELAXED, __HIP_MEMORY_SCOPE_AGENT);
    } else {
      while (__hip_atomic_load(grpGo, __ATOMIC_RELAXED, __HIP_MEMORY_SCOPE_AGENT) < phase)
        __builtin_amdgcn_s_sleep(4);
    }
  }
  __syncthreads();
}

__global__ __launch_bounds__(512, 2) void gruPersist(GruParams p) {
  const int tid  = threadIdx.x;
  const int bid  = blockIdx.x;
  const int w    = tid >> 6;        // wave 0..7
  const int lane = tid & 63;
  const int b    = lane & 31;       // batch
  const int ks   = lane >> 5;       // k-subslice 0/1
  const int jbase = bid << 2;
  float* scratch = lds + WFLOATS;

  // ---- cache this block's Wh slices in LDS (coalesced, cached loads) ----
  for (int idx = tid; idx < WFLOATS; idx += 512) {
    const int slice = idx >> 12;           // layer*3 + gate
    const int rem   = idx & 4095;          // jj*1024 + k
    const int l = slice / 3, m = slice - l * 3;
    lds[idx] = p.Wh[l][m][((size_t)jbase << 10) + rem];
  }
  __syncthreads();

  unsigned phase = 0;
  float my_z = 0.f, my_gx = 0.f;    // valid for tid<128, carried A->C

  for (int t = 0; t < 512; ++t) {
    for (int l = 0; l < 3; ++l) {
      float* hTl = p.hT + l * 32768;

      // ================= Stage A =================
      float az[4] = {0.f,0.f,0.f,0.f};
      float ar[4] = {0.f,0.f,0.f,0.f};
      float ag[4] = {0.f,0.f,0.f,0.f};

      // h-side (K=1024): activations via MALL, weights from LDS
      {
        const float* wzl = lds + (l * 3 + 0) * 4096;
        const float* wrl = lds + (l * 3 + 1) * 4096;
        #pragma unroll 4
        for (int i = 0; i < 16; ++i) {
          const int k = (w << 7) + (i << 3) + (ks << 2);
          const float o0 = loadc(hTl + (k + 0) * 32 + b);
          const float o1 = loadc(hTl + (k + 1) * 32 + b);
          const float o2 = loadc(hTl + (k + 2) * 32 + b);
          const float o3 = loadc(hTl + (k + 3) * 32 + b);
          #pragma unroll
          for (int jj = 0; jj < 4; ++jj) {
            const float4 a = *(const float4*)(wzl + (jj << 10) + k);
            const float4 c = *(const float4*)(wrl + (jj << 10) + k);
            az[jj] += o0 * a.x; az[jj] += o1 * a.y;
            az[jj] += o2 * a.z; az[jj] += o3 * a.w;
            ar[jj] += o0 * c.x; ar[jj] += o1 * c.y;
            ar[jj] += o2 * c.z; ar[jj] += o3 * c.w;
          }
        }
      }

      // x-side
      if (l == 0) {
        const float* xb = p.x + ((size_t)b << 16) + ((size_t)t << 7);
        #pragma unroll
        for (int i = 0; i < 2; ++i) {
          const int k = (w << 4) + (i << 3) + (ks << 2);
          const float o0 = xb[k + 0], o1 = xb[k + 1];
          const float o2 = xb[k + 2], o3 = xb[k + 3];
          #pragma unroll
          for (int jj = 0; jj < 4; ++jj) {
            const size_t row = (size_t)(jbase + jj) * 128 + k;
            const float4 a = *(const float4*)(p.Wx[0][0] + row);
            const float4 c = *(const float4*)(p.Wx[0][1] + row);
            const float4 d = *(const float4*)(p.Wx[0][2] + row);
            az[jj] += o0 * a.x; az[jj] += o1 * a.y;
            az[jj] += o2 * a.z; az[jj] += o3 * a.w;
            ar[jj] += o0 * c.x; ar[jj] += o1 * c.y;
            ar[jj] += o2 * c.z; ar[jj] += o3 * c.w;
            ag[jj] += o0 * d.x; ag[jj] += o1 * d.y;
            ag[jj] += o2 * d.z; ag[jj] += o3 * d.w;
          }
        }
      } else {
        const float* inT = p.hT + (l - 1) * 32768;
        const float* wxz = p.Wx[l][0];
        const float* wxr = p.Wx[l][1];
        const float* wxg = p.Wx[l][2];
        #pragma unroll 2
        for (int i = 0; i < 16; ++i) {
          const int k = (w << 7) + (i << 3) + (ks << 2);
          const float o0 = loadc(inT + (k + 0) * 32 + b);
          const float o1 = loadc(inT + (k + 1) * 32 + b);
          const float o2 = loadc(inT + (k + 2) * 32 + b);
          const float o3 = loadc(inT + (k + 3) * 32 + b);
          #pragma unroll
          for (int jj = 0; jj < 4; ++jj) {
            const size_t row = ((size_t)(jbase + jj) << 10) + k;
            const float4 a = *(const float4*)(wxz + row);
            const float4 c = *(const float4*)(wxr + row);
            const float4 d = *(const float4*)(wxg + row);
            az[jj] += o0 * a.x; az[jj] += o1 * a.y;
            az[jj] += o2 * a.z; az[jj] += o3 * a.w;
            ar[jj] += o0 * c.x; ar[jj] += o1 * c.y;
            ar[jj] += o2 * c.z; ar[jj] += o3 * c.w;
            ag[jj] += o0 * d.x; ag[jj] += o1 * d.y;
            ag[jj] += o2 * d.z; ag[jj] += o3 * d.w;
          }
        }
      }

      // reduce: ks pair, then 8 waves via LDS
      #pragma unroll
      for (int jj = 0; jj < 4; ++jj) {
        az[jj] += __shfl_xor(az[jj], 32);
        ar[jj] += __shfl_xor(ar[jj], 32);
        ag[jj] += __shfl_xor(ag[jj], 32);
      }
      if (ks == 0) {
        #pragma unroll
        for (int jj = 0; jj < 4; ++jj) {
          scratch[w * 384 + (jj * 3 + 0) * 32 + b] = az[jj];
          scratch[w * 384 + (jj * 3 + 1) * 32 + b] = ar[jj];
          scratch[w * 384 + (jj * 3 + 2) * 32 + b] = ag[jj];
        }
      }
      __syncthreads();
      if (tid < 384) {
        float s = 0.f;
        #pragma unroll
        for (int ww = 0; ww < 8; ++ww) s += scratch[ww * 384 + tid];
        scratch[3072 + tid] = s;
      }
      __syncthreads();
      if (tid < 128) {
        const int jj = tid >> 5, bb = tid & 31;
        const int j = jbase + jj;
        const float zp = scratch[3072 + (jj * 3 + 0) * 32 + bb] + p.bias[l][0][j];
        const float rp = scratch[3072 + (jj * 3 + 1) * 32 + bb] + p.bias[l][1][j];
        const float gp = scratch[3072 + (jj * 3 + 2) * 32 + bb] + p.bias[l][2][j];
        const float z = 1.f / (1.f + expf(-zp));
        const float r = 1.f / (1.f + expf(-rp));
        my_z  = z;
        my_gx = gp;
        storec(p.rhT + (j << 5) + bb, r * loadc(hTl + (j << 5) + bb));
      }
      ++phase;
      gridbar(p.bar, phase, bid);

      // ================= Stage C =================
      float ac[4] = {0.f,0.f,0.f,0.f};
      {
        const float* wgl = lds + (l * 3 + 2) * 4096;
        #pragma unroll 4
        for (int i = 0; i < 16; ++i) {
          const int k = (w << 7) + (i << 3) + (ks << 2);
          const float o0 = loadc(p.rhT + (k + 0) * 32 + b);
          const float o1 = loadc(p.rhT + (k + 1) * 32 + b);
          const float o2 = loadc(p.rhT + (k + 2) * 32 + b);
          const float o3 = loadc(p.rhT + (k + 3) * 32 + b);
          #pragma unroll
          for (int jj = 0; jj < 4; ++jj) {
            const float4 g4 = *(const float4*)(wgl + (jj << 10) + k);
            ac[jj] += o0 * g4.x; ac[jj] += o1 * g4.y;
            ac[jj] += o2 * g4.z; ac[jj] += o3 * g4.w;
          }
        }
      }
      #pragma unroll
      for (int jj = 0; jj < 4; ++jj) ac[jj] += __shfl_xor(ac[jj], 32);
      if (ks == 0) {
        #pragma unroll
        for (int jj = 0; jj < 4; ++jj)
          scratch[w * 128 + jj * 32 + b] = ac[jj];
      }
      __syncthreads();
      if (tid < 128) {
        float s = 0.f;
        #pragma unroll
        for (int ww = 0; ww < 8; ++ww) s += scratch[ww * 128 + tid];
        const int jj = tid >> 5, bb = tid & 31;
        const int j = jbase + jj;
        const float g  = tanhf(s + my_gx);
        const float hn = my_z * loadc(hTl + (j << 5) + bb) + (1.f - my_z) * g;
        storec(hTl + (j << 5) + bb, hn);
        if (t == 511) p.outHid[bb * 3072 + l * 1024 + j] = hn;
      }
      ++phase;
      gridbar(p.bar, phase, bid);
    } // layers

    // ================= Output head (blocks 0..31) =================
    if (bid < 32) {
      const float* h2 = p.hT + 2 * 32768;
      const int obase = bid << 2;
      float ac[4] = {0.f,0.f,0.f,0.f};
      #pragma unroll 2
      for (int i = 0; i < 16; ++i) {
        const int k = (w << 7) + (i << 3) + (ks << 2);
        const float o0 = loadc(h2 + (k + 0) * 32 + b);
        const float o1 = loadc(h2 + (k + 1) * 32 + b);
        const float o2 = loadc(h2 + (k + 2) * 32 + b);
        const float o3 = loadc(h2 + (k + 3) * 32 + b);
        #pragma unroll
        for (int oo = 0; oo < 4; ++oo) {
          const float4 wv = *(const float4*)(p.Wout + ((size_t)(obase + oo) << 10) + k);
          ac[oo] += o0 * wv.x; ac[oo] += o1 * wv.y;
          ac[oo] += o2 * wv.z; ac[oo] += o3 * wv.w;
        }
      }
      #pragma unroll
      for (int oo = 0; oo < 4; ++oo) ac[oo] += __shfl_xor(ac[oo], 32);
      if (ks == 0) {
        #pragma unroll
        for (int oo = 0; oo < 4; ++oo)
          scratch[w * 128 + oo * 32 + b] = ac[oo];
      }
      __syncthreads();
      if (tid < 128) {
        float s = 0.f;
        #pragma unroll
        for (int ww = 0; ww < 8; ++ww) s += scratch[ww * 128 + tid];
        const int oo = tid >> 5, bb = tid & 31;
        const int o = obase + oo;
        p.out[((size_t)bb << 16) + ((size_t)t << 7) + o] = s + p.bout[o];
      }
      __syncthreads();   // protect scratch before next timestep's stage A
    }
  } // t
}

// Zero h-state and barrier region (ws is poisoned 0xAA before every launch).
__global__ void initWs(float* hT, unsigned* bar) {
  const int i = blockIdx.x * 1024 + threadIdx.x;
  if (i < 98304) hT[i] = 0.f;
  if (i < 2048) bar[i] = 0u;
}

extern "C" void kernel_launch(void* const* d_in, const int* in_sizes, int n_in,
                              void* d_out, int out_size, void* d_ws, size_t ws_size,
                              hipStream_t stream)
{
  GruParams P;
  P.x = (const float*)d_in[0];
  P.Wx[0][0] = (const float*)d_in[1];  P.Wh[0][0] = (const float*)d_in[2];
  P.bias[0][0] = (const float*)d_in[3];
  P.Wx[0][1] = (const float*)d_in[4];  P.Wh[0][1] = (const float*)d_in[5];
  P.bias[0][1] = (const float*)d_in[6];
  P.Wx[0][2] = (const float*)d_in[7];  P.Wh[0][2] = (const float*)d_in[8];
  P.bias[0][2] = (const float*)d_in[9];
  for (int l = 1; l < 3; ++l) {
    const size_t off = (size_t)(l - 1) * 1048576;
    const size_t ob  = (size_t)(l - 1) * 1024;
    P.Wx[l][0] = (const float*)d_in[10] + off; P.Wh[l][0] = (const float*)d_in[11] + off;
    P.bias[l][0] = (const float*)d_in[12] + ob;
    P.Wx[l][1] = (const float*)d_in[13] + off; P.Wh[l][1] = (const float*)d_in[14] + off;
    P.bias[l][1] = (const float*)d_in[15] + ob;
    P.Wx[l][2] = (const float*)d_in[16] + off; P.Wh[l][2] = (const float*)d_in[17] + off;
    P.bias[l][2] = (const float*)d_in[18] + ob;
  }
  P.Wout = (const float*)d_in[19];
  P.bout = (const float*)d_in[20];

  float* ws = (float*)d_ws;
  P.hT  = ws;                          // 3*32768 f32
  P.rhT = ws + 98304;                  // 32768 f32
  P.bar = (unsigned*)(ws + 131072);    // 2048 uints barrier region
  P.out = (float*)d_out;
  P.outHid = P.out + 2097152;

  hipFuncSetAttribute(reinterpret_cast<const void*>(gruPersist),
                      hipFuncAttributeMaxDynamicSharedMemorySize, LDSB);

  initWs<<<96, 1024, 0, stream>>>(P.hT, P.bar);
  gruPersist<<<NBLK, 512, LDSB, stream>>>(P);
}